// Round 15
// baseline (300.729 us; speedup 1.0000x reference)
//
#include <hip/hip_runtime.h>

// Vector quantization: z [32768,256] f32, codebook [8192,256] f32
// outputs: z_q [32768,256] f32, indices [32768] (as float)
//
// bf16 MFMA screen (MARGIN=4.5e-4) + exact resolve with the bitwise round-2
// f32 chain (absmax 0 in rounds 2-14).
// Screen v9 = round-8/10 structure (64 rows/wave, reg-streamed B) with
// TRIPLE-buffered B (prefetch depth 2, ~2400 cyc cover) to absorb L2
// return-queue spikes. Single acc set (ping-pong was neutral, r14).

#define NROWS 32768
#define DIM   256
#define KCB   8192
#define CANDCAP 128
#define MARGIN  4.5e-4f
#define WBUF    320

// scratch byte offsets (from scratch base SB = d_ws or d_out)
#define SB_CAND  0u          // u16 [32768][128]  8 MB
#define SB_CNT   8388608u    // u32 [32768]
#define SB_ZSQ   8519680u    // f32 [32768]
#define SB_CSQ   8650752u    // f32 [8192]
#define SB_CSQ1  8683520u    // f32 [8192]
#define SB_OVL   8716288u    // u32 [32768]
#define SB_OVC   8847360u    // u32 (+pad)
#define SB_IMG   8847424u    // B tile image [T 512][kk 8][lane 64]x16B = 4 MB
#define SB_NEED  13041728u   // img end

using bf16x8 = __attribute__((ext_vector_type(8))) short;
using f32x4  = __attribute__((ext_vector_type(4))) float;
using u32x4  = __attribute__((ext_vector_type(4))) unsigned int;

__device__ __forceinline__ unsigned short bf16rne(float f) {
    unsigned u = __float_as_uint(f);
    unsigned r = u + 0x7FFFu + ((u >> 16) & 1u);
    return (unsigned short)(r >> 16);
}

__device__ __forceinline__ unsigned pack2_bf16(float a, float b) {
    return (unsigned)bf16rne(a) | ((unsigned)bf16rne(b) << 16);
}

// numpy pairwise sum of squares, n=256, bitwise-faithful (rounds 2-14).
__device__ float np_sumsq_256(const float* __restrict__ p) {
#pragma clang fp contract(off)
    float blk[2];
    #pragma unroll
    for (int b = 0; b < 2; ++b) {
        const float4* q4 = reinterpret_cast<const float4*>(p + b * 128);
        float4 a0 = q4[0], a1 = q4[1];
        float r[8];
        r[0] = __fmul_rn(a0.x, a0.x); r[1] = __fmul_rn(a0.y, a0.y);
        r[2] = __fmul_rn(a0.z, a0.z); r[3] = __fmul_rn(a0.w, a0.w);
        r[4] = __fmul_rn(a1.x, a1.x); r[5] = __fmul_rn(a1.y, a1.y);
        r[6] = __fmul_rn(a1.z, a1.z); r[7] = __fmul_rn(a1.w, a1.w);
        #pragma unroll
        for (int i = 2; i < 32; i += 2) {
            a0 = q4[i]; a1 = q4[i + 1];
            r[0] = __fadd_rn(r[0], __fmul_rn(a0.x, a0.x));
            r[1] = __fadd_rn(r[1], __fmul_rn(a0.y, a0.y));
            r[2] = __fadd_rn(r[2], __fmul_rn(a0.z, a0.z));
            r[3] = __fadd_rn(r[3], __fmul_rn(a0.w, a0.w));
            r[4] = __fadd_rn(r[4], __fmul_rn(a1.x, a1.x));
            r[5] = __fadd_rn(r[5], __fmul_rn(a1.y, a1.y));
            r[6] = __fadd_rn(r[6], __fmul_rn(a1.z, a1.z));
            r[7] = __fadd_rn(r[7], __fmul_rn(a1.w, a1.w));
        }
        blk[b] = __fadd_rn(
            __fadd_rn(__fadd_rn(r[0], r[1]), __fadd_rn(r[2], r[3])),
            __fadd_rn(__fadd_rn(r[4], r[5]), __fadd_rn(r[6], r[7])));
    }
    return __fadd_rn(blk[0], blk[1]);
}

// Fused prep: B tile image convert + csq/csq1 + zsq + counter init.
// B image: [T 512][kk 8][s 64] x 16B; s = lhi*16 + code, content = bf16x8 of
// cb[T*16+code][kk*32+lhi*8 .. +8).
__global__ void vq_prep_kernel(const float* __restrict__ z,
                               const float* __restrict__ cb,
                               char* __restrict__ img,
                               float* __restrict__ zsq, float* __restrict__ csq,
                               float* __restrict__ csq1,
                               unsigned* __restrict__ cnt, unsigned* __restrict__ ovc) {
    int t = blockIdx.x * 256 + threadIdx.x;
    if (t < NROWS) cnt[t] = 0;
    if (t == 0) *ovc = 0;
    if (t < 262144) {
        int s = t & 63, kk = (t >> 6) & 7, T = t >> 9;
        int code = s & 15, lhi = s >> 4;
        const float* src = cb + (size_t)(T * 16 + code) * DIM + kk * 32 + lhi * 8;
        float4 v0 = *reinterpret_cast<const float4*>(src);
        float4 v1 = *reinterpret_cast<const float4*>(src + 4);
        uint4 o;
        o.x = pack2_bf16(v0.x, v0.y); o.y = pack2_bf16(v0.z, v0.w);
        o.z = pack2_bf16(v1.x, v1.y); o.w = pack2_bf16(v1.z, v1.w);
        *reinterpret_cast<uint4*>(img + (size_t)T * 8192 + kk * 1024 + s * 16) = o;
    } else if (t < 262144 + KCB) {
        int k = t - 262144;
        float s = np_sumsq_256(cb + (size_t)k * DIM);
        csq[k] = s;
        csq1[k] = s + 1.0f;
    } else if (t < 262144 + KCB + NROWS) {
        int r = t - 262144 - KCB;
        zsq[r] = np_sumsq_256(z + (size_t)r * DIM);
    }
}

// ---------------- register-streamed MFMA screen, triple-buffered B ----------
// Grid 256 x 512 thr (8 waves = 2 wr x 4 wc). Wave: 64 rows x 2048 codes as
// 128 16-code tiles. Tile t uses buffer t%3; load for t+2 issues at t.
__global__ __launch_bounds__(512, 2) void vq_screen_kernel(
    const float* __restrict__ z, const char* __restrict__ img,
    const float* __restrict__ csq1,
    unsigned* __restrict__ cnt, unsigned short* __restrict__ cand) {
    __shared__ unsigned runmin[128];
    __shared__ unsigned wcnt[8];
    __shared__ unsigned wbuf[8][WBUF];
    const int tid = threadIdx.x, lane = tid & 63, wid = tid >> 6;
    const int wr = wid >> 2, wc = wid & 3;
    const int l15 = lane & 15, lhi = lane >> 4;
    const int row0 = blockIdx.x * 128;
    const int tbase = wc * 128;

    // A fragments (one-time bf16 convert from raw z)
    bf16x8 ah[4][8];
    #pragma unroll
    for (int m = 0; m < 4; ++m) {
        const float* zr = z + (size_t)(row0 + wr * 64 + m * 16 + l15) * DIM;
        #pragma unroll
        for (int kk = 0; kk < 8; ++kk) {
            float4 v0 = *reinterpret_cast<const float4*>(zr + kk * 32 + lhi * 8);
            float4 v1 = *reinterpret_cast<const float4*>(zr + kk * 32 + lhi * 8 + 4);
            uint4 o;
            o.x = pack2_bf16(v0.x, v0.y); o.y = pack2_bf16(v0.z, v0.w);
            o.z = pack2_bf16(v1.x, v1.y); o.w = pack2_bf16(v1.z, v1.w);
            ah[m][kk] = __builtin_bit_cast(bf16x8, o);
        }
    }

    if (tid < 128) runmin[tid] = 0x7F800000u;   // +inf (s'' > 0 -> uint-monotone)
    if (tid < 8) wcnt[tid] = 0;
    __syncthreads();                            // the only block barrier

    f32x4 acc[4];
    #pragma unroll
    for (int m = 0; m < 4; ++m) acc[m] = (f32x4){0.f, 0.f, 0.f, 0.f};

    const char*  gp  = img + (size_t)tbase * 8192 + (size_t)lane * 16;
    const float* cpe = csq1 + tbase * 16 + l15;
    int codeb = tbase * 16 + l15;

    u32x4 bA[8], bB[8], bC[8];

    auto PUSH = [&](int lr, int code) {
        unsigned pi = atomicAdd(&wcnt[wid], 1u);
        if (pi < WBUF) wbuf[wid][pi] = ((unsigned)lr << 13) | (unsigned)code;
        else {
            int grow = row0 + lr;
            unsigned gs = atomicAdd(&cnt[grow], 1u);
            if (gs < CANDCAP) cand[(size_t)grow * CANDCAP + gs] = (unsigned short)code;
        }
    };

#define LOADR(bh)                                                         \
    {                                                                     \
        _Pragma("unroll")                                                 \
        for (int kk = 0; kk < 8; ++kk)                                    \
            bh[kk] = *reinterpret_cast<const u32x4*>(gp + kk * 1024);     \
        gp += 8192;                                                       \
    }

#define MFMAS(bh)                                                         \
    {                                                                     \
        _Pragma("unroll")                                                 \
        for (int kk = 0; kk < 8; ++kk) {                                  \
            bf16x8 bv = __builtin_bit_cast(bf16x8, bh[kk]);               \
            _Pragma("unroll")                                             \
            for (int m = 0; m < 4; ++m)                                   \
                acc[m] = __builtin_amdgcn_mfma_f32_16x16x32_bf16(         \
                    ah[m][kk], bv, acc[m], 0, 0, 0);                      \
        }                                                                 \
    }

#define EPI()                                                             \
    {                                                                     \
        const float csv = *cpe; cpe += 16;                                \
        _Pragma("unroll")                                                 \
        for (int m = 0; m < 4; ++m) {                                     \
            const int lr0 = wr * 64 + m * 16 + lhi * 4;                   \
            uint4 rmb = *reinterpret_cast<const uint4*>(&runmin[lr0]);    \
            float s0 = fmaf(acc[m][0], -2.0f, csv);                       \
            float s1 = fmaf(acc[m][1], -2.0f, csv);                       \
            float s2 = fmaf(acc[m][2], -2.0f, csv);                       \
            float s3 = fmaf(acc[m][3], -2.0f, csv);                       \
            bool c0 = s0 < __uint_as_float(rmb.x) + MARGIN;               \
            bool c1 = s1 < __uint_as_float(rmb.y) + MARGIN;               \
            bool c2 = s2 < __uint_as_float(rmb.z) + MARGIN;               \
            bool c3 = s3 < __uint_as_float(rmb.w) + MARGIN;               \
            if (__any(c0 | c1 | c2 | c3)) {                               \
                if (c0) { if (s0 < __uint_as_float(rmb.x)) atomicMin(&runmin[lr0 + 0], __float_as_uint(s0)); PUSH(lr0 + 0, codeb); } \
                if (c1) { if (s1 < __uint_as_float(rmb.y)) atomicMin(&runmin[lr0 + 1], __float_as_uint(s1)); PUSH(lr0 + 1, codeb); } \
                if (c2) { if (s2 < __uint_as_float(rmb.z)) atomicMin(&runmin[lr0 + 2], __float_as_uint(s2)); PUSH(lr0 + 2, codeb); } \
                if (c3) { if (s3 < __uint_as_float(rmb.w)) atomicMin(&runmin[lr0 + 3], __float_as_uint(s3)); PUSH(lr0 + 3, codeb); } \
            }                                                             \
            acc[m] = (f32x4){0.f, 0.f, 0.f, 0.f};                         \
        }                                                                 \
        codeb += 16;                                                      \
    }

    // prologue: tiles 0,1 in flight
    LOADR(bA);                       // tile 0
    LOADR(bB);                       // tile 1
    // t = 0: issue tile 2, compute tile 0, self-bound epilogue
    LOADR(bC);
    MFMAS(bA);
    {
        const float csv = *cpe; cpe += 16;
        #pragma unroll
        for (int m = 0; m < 4; ++m) {
            const int lr0 = wr * 64 + m * 16 + lhi * 4;
            #pragma unroll
            for (int r = 0; r < 4; ++r) {
                float s2 = fmaf(acc[m][r], -2.0f, csv);
                float sm = s2;
                sm = fminf(sm, __shfl_xor(sm, 1));
                sm = fminf(sm, __shfl_xor(sm, 2));
                sm = fminf(sm, __shfl_xor(sm, 4));
                sm = fminf(sm, __shfl_xor(sm, 8));
                if (l15 == 0) atomicMin(&runmin[lr0 + r], __float_as_uint(sm));
                if (s2 < sm + MARGIN) PUSH(lr0 + r, codeb);
            }
            acc[m] = (f32x4){0.f, 0.f, 0.f, 0.f};
        }
        codeb += 16;
    }

    // steady state: t = 3g+1, 3g+2, 3g+3 for g = 0..40  (t = 1..123)
    for (int g = 0; g < 41; ++g) {
        LOADR(bA);  MFMAS(bB);  EPI();   // t=3g+1, load tile t+2 -> bA
        LOADR(bB);  MFMAS(bC);  EPI();   // t=3g+2 -> bB
        LOADR(bC);  MFMAS(bA);  EPI();   // t=3g+3 -> bC
    }
    // tail: t = 124..127 (loads for 126,127 only)
    LOADR(bA);  MFMAS(bB);  EPI();       // t=124, load 126
    LOADR(bB);  MFMAS(bC);  EPI();       // t=125, load 127
    MFMAS(bA);  EPI();                   // t=126
    MFMAS(bB);  EPI();                   // t=127

    // flush wave-local candidate buffer to global per-row lists
    unsigned n = wcnt[wid]; if (n > WBUF) n = WBUF;
    for (unsigned e = lane; e < n; e += 64) {
        unsigned u = wbuf[wid][e];
        int row = row0 + (int)(u >> 13);
        int code = (int)(u & 8191u);
        unsigned slot = atomicAdd(&cnt[row], 1u);
        if (slot < CANDCAP) cand[(size_t)row * CANDCAP + slot] = (unsigned short)code;
    }
#undef LOADR
#undef MFMAS
#undef EPI
}

// ---------------- exact resolve (rounds 6-14 chain) + fused gather ----------
__global__ __launch_bounds__(256) void vq_exact_kernel(
    const float* __restrict__ z, const float* __restrict__ cb,
    const float* __restrict__ zsq, const float* __restrict__ csq,
    const unsigned* __restrict__ cnt, const unsigned short* __restrict__ cand,
    unsigned* __restrict__ ovl, unsigned* __restrict__ ovc,
    float* __restrict__ idxF, float4* __restrict__ outz, int fused) {
    __shared__ float zrow[4][DIM];
    const int wid = threadIdx.x >> 6, lane = threadIdx.x & 63;
    const int row = blockIdx.x * 4 + wid;

    float4 zv4 = *reinterpret_cast<const float4*>(&z[(size_t)row * DIM + lane * 4]);
    *reinterpret_cast<float4*>(&zrow[wid][lane * 4]) = zv4;
    __syncthreads();

    const unsigned c = cnt[row];
    if (c == 0 || c > CANDCAP) {
        if (lane == 0) { unsigned s = atomicAdd(ovc, 1u); ovl[s] = row; }
        return;
    }

    const float Zr = zsq[row];
    const float4* cb4 = reinterpret_cast<const float4*>(cb);
    float best = 3.4e38f;
    int   bi   = 0x7FFFFFFF;

    for (int j = lane; j < (int)c; j += 64) {
        int k = cand[(size_t)row * CANDCAP + j];
        float a = 0.0f;
        #pragma unroll 8
        for (int q = 0; q < 64; ++q) {
            float4 cv = cb4[(size_t)k * 64 + q];
            float4 zv = *reinterpret_cast<const float4*>(&zrow[wid][q * 4]);
            a = fmaf(zv.x, cv.x, a); a = fmaf(zv.y, cv.y, a);
            a = fmaf(zv.z, cv.z, a); a = fmaf(zv.w, cv.w, a);
        }
        float sv = __fadd_rn(__fsub_rn(Zr, __fmul_rn(2.0f, a)), csq[k]);
        if (sv < best || (sv == best && k < bi)) { best = sv; bi = k; }
    }
    #pragma unroll
    for (int mk = 32; mk >= 1; mk >>= 1) {
        float ov = __shfl_xor(best, mk);
        int   oi = __shfl_xor(bi, mk);
        if (ov < best || (ov == best && oi < bi)) { best = ov; bi = oi; }
    }
    if (lane == 0) idxF[row] = (float)bi;
    if (fused) outz[(size_t)row * 64 + lane] = cb4[(size_t)bi * 64 + lane];
}

// Full scan for overflow rows (expected 0). Bitwise chain, first-index ties.
__global__ __launch_bounds__(256) void vq_cleanup_kernel(
    const float* __restrict__ z, const float* __restrict__ cb,
    const float* __restrict__ zsq, const float* __restrict__ csq,
    const unsigned* __restrict__ ovl, const unsigned* __restrict__ ovc,
    float* __restrict__ idxF, float4* __restrict__ outz, int fused) {
    __shared__ float zrow[DIM];
    __shared__ float wv[4]; __shared__ int wi[4];
    __shared__ int sbi;
    const int lane = threadIdx.x & 63, wid = threadIdx.x >> 6;
    const unsigned count = *ovc;
    for (unsigned w = blockIdx.x; w < count; w += gridDim.x) {
        const int row = ovl[w];
        __syncthreads();
        *reinterpret_cast<float4*>(&zrow[threadIdx.x * 4 & (DIM - 1)]) =
            *reinterpret_cast<const float4*>(&z[(size_t)row * DIM + (threadIdx.x * 4 & (DIM - 1))]);
        __syncthreads();
        const float Zr = zsq[row];
        const float4* cb4 = reinterpret_cast<const float4*>(cb);
        float best = 3.4e38f; int bi = 0x7FFFFFFF;
        for (int k = threadIdx.x; k < KCB; k += 256) {
            float a = 0.0f;
            #pragma unroll 8
            for (int q = 0; q < 64; ++q) {
                float4 cv = cb4[(size_t)k * 64 + q];
                float4 zv = *reinterpret_cast<const float4*>(&zrow[q * 4]);
                a = fmaf(zv.x, cv.x, a); a = fmaf(zv.y, cv.y, a);
                a = fmaf(zv.z, cv.z, a); a = fmaf(zv.w, cv.w, a);
            }
            float sv = __fadd_rn(__fsub_rn(Zr, __fmul_rn(2.0f, a)), csq[k]);
            if (sv < best || (sv == best && k < bi)) { best = sv; bi = k; }
        }
        #pragma unroll
        for (int mk = 32; mk >= 1; mk >>= 1) {
            float ov = __shfl_xor(best, mk);
            int   oi = __shfl_xor(bi, mk);
            if (ov < best || (ov == best && oi < bi)) { best = ov; bi = oi; }
        }
        if (lane == 0) { wv[wid] = best; wi[wid] = bi; }
        __syncthreads();
        if (threadIdx.x == 0) {
            #pragma unroll
            for (int u = 1; u < 4; ++u)
                if (wv[u] < best || (wv[u] == best && wi[u] < bi)) { best = wv[u]; bi = wi[u]; }
            idxF[row] = (float)bi;
            sbi = bi;
        }
        __syncthreads();
        if (fused && threadIdx.x < 64)
            outz[(size_t)row * 64 + threadIdx.x] = cb4[(size_t)sbi * 64 + threadIdx.x];
    }
}

__global__ void vq_gather_kernel(const float* __restrict__ cb,
                                 const float* __restrict__ idxF,
                                 float4* __restrict__ out4) {
    int g = blockIdx.x * blockDim.x + threadIdx.x;
    const float4* cb4 = reinterpret_cast<const float4*>(cb);
    for (int i = g; i < NROWS * 64; i += gridDim.x * blockDim.x) {
        int row = i >> 6, q = i & 63;
        int idx = (int)idxF[row];
        out4[i] = cb4[(size_t)idx * 64 + q];
    }
}

extern "C" void kernel_launch(void* const* d_in, const int* in_sizes, int n_in,
                              void* d_out, int out_size, void* d_ws, size_t ws_size,
                              hipStream_t stream) {
    const float* z  = (const float*)d_in[0];
    const float* cb = (const float*)d_in[1];
    float* out = (float*)d_out;

    const int fused = (ws_size >= (size_t)SB_NEED) ? 1 : 0;
    char* SB = fused ? (char*)d_ws : (char*)d_out;

    unsigned short* candp = (unsigned short*)(SB + SB_CAND);
    unsigned*       cntp  = (unsigned*)(SB + SB_CNT);
    float*          zsq   = (float*)(SB + SB_ZSQ);
    float*          csq   = (float*)(SB + SB_CSQ);
    float*          csq1  = (float*)(SB + SB_CSQ1);
    unsigned*       ovl   = (unsigned*)(SB + SB_OVL);
    unsigned*       ovc   = (unsigned*)(SB + SB_OVC);
    char*           img   = SB + SB_IMG;
    float*          idxF  = out + 8388608;   // output 1 (indices as float)

    vq_prep_kernel<<<(262144 + KCB + NROWS + 255) / 256, 256, 0, stream>>>(
        z, cb, img, zsq, csq, csq1, cntp, ovc);
    vq_screen_kernel<<<NROWS / 128, 512, 0, stream>>>(z, img, csq1, cntp, candp);
    vq_exact_kernel<<<NROWS / 4, 256, 0, stream>>>(
        z, cb, zsq, csq, cntp, candp, ovl, ovc, idxF, (float4*)out, fused);
    vq_cleanup_kernel<<<64, 256, 0, stream>>>(
        z, cb, zsq, csq, ovl, ovc, idxF, (float4*)out, fused);
    if (!fused)
        vq_gather_kernel<<<2048, 256, 0, stream>>>(cb, idxF, (float4*)out);
}

// Round 16
// 289.248 us; speedup vs baseline: 1.0397x; 1.0397x over previous
//
#include <hip/hip_runtime.h>

// Vector quantization: z [32768,256] f32, codebook [8192,256] f32
// outputs: z_q [32768,256] f32, indices [32768] (as float)
//
// bf16 MFMA screen (MARGIN=4.5e-4) + exact resolve with the bitwise round-2
// f32 chain (absmax 0 in rounds 2-15).
// v10: screen = round-9 double-buffer config (the measured 187 us plateau;
// deeper prefetch spills, r15). Tail slimmed: prep no longer reads z at all;
// exact/cleanup compute Zr from their LDS zrow copy with the same bitwise
// np-pairwise chain (identical bits in, identical op order -> identical Zr).

#define NROWS 32768
#define DIM   256
#define KCB   8192
#define CANDCAP 128
#define MARGIN  4.5e-4f
#define WBUF    320

// scratch byte offsets (from scratch base SB = d_ws or d_out)
#define SB_CAND  0u          // u16 [32768][128]  8 MB
#define SB_CNT   8388608u    // u32 [32768]
#define SB_CSQ   8519680u    // f32 [8192]
#define SB_CSQ1  8552448u    // f32 [8192]
#define SB_OVL   8585216u    // u32 [32768]
#define SB_OVC   8716288u    // u32 (+pad)
#define SB_IMG   8716304u    // B tile image [T 512][kk 8][lane 64]x16B = 4 MB
#define SB_NEED  12910608u   // img end

using bf16x8 = __attribute__((ext_vector_type(8))) short;
using f32x4  = __attribute__((ext_vector_type(4))) float;
using u32x4  = __attribute__((ext_vector_type(4))) unsigned int;

__device__ __forceinline__ unsigned short bf16rne(float f) {
    unsigned u = __float_as_uint(f);
    unsigned r = u + 0x7FFFu + ((u >> 16) & 1u);
    return (unsigned short)(r >> 16);
}

__device__ __forceinline__ unsigned pack2_bf16(float a, float b) {
    return (unsigned)bf16rne(a) | ((unsigned)bf16rne(b) << 16);
}

// numpy pairwise sum of squares, n=256, bitwise-faithful (rounds 2-15).
// Works on any f32 array with the exact source bits (global z or LDS copy).
__device__ float np_sumsq_256(const float* __restrict__ p) {
#pragma clang fp contract(off)
    float blk[2];
    #pragma unroll
    for (int b = 0; b < 2; ++b) {
        const float4* q4 = reinterpret_cast<const float4*>(p + b * 128);
        float4 a0 = q4[0], a1 = q4[1];
        float r[8];
        r[0] = __fmul_rn(a0.x, a0.x); r[1] = __fmul_rn(a0.y, a0.y);
        r[2] = __fmul_rn(a0.z, a0.z); r[3] = __fmul_rn(a0.w, a0.w);
        r[4] = __fmul_rn(a1.x, a1.x); r[5] = __fmul_rn(a1.y, a1.y);
        r[6] = __fmul_rn(a1.z, a1.z); r[7] = __fmul_rn(a1.w, a1.w);
        #pragma unroll
        for (int i = 2; i < 32; i += 2) {
            a0 = q4[i]; a1 = q4[i + 1];
            r[0] = __fadd_rn(r[0], __fmul_rn(a0.x, a0.x));
            r[1] = __fadd_rn(r[1], __fmul_rn(a0.y, a0.y));
            r[2] = __fadd_rn(r[2], __fmul_rn(a0.z, a0.z));
            r[3] = __fadd_rn(r[3], __fmul_rn(a0.w, a0.w));
            r[4] = __fadd_rn(r[4], __fmul_rn(a1.x, a1.x));
            r[5] = __fadd_rn(r[5], __fmul_rn(a1.y, a1.y));
            r[6] = __fadd_rn(r[6], __fmul_rn(a1.z, a1.z));
            r[7] = __fadd_rn(r[7], __fmul_rn(a1.w, a1.w));
        }
        blk[b] = __fadd_rn(
            __fadd_rn(__fadd_rn(r[0], r[1]), __fadd_rn(r[2], r[3])),
            __fadd_rn(__fadd_rn(r[4], r[5]), __fadd_rn(r[6], r[7])));
    }
    return __fadd_rn(blk[0], blk[1]);
}

// Prep: cb-only (B tile image + csq/csq1) + counter init. z untouched.
// B image: [T 512][kk 8][s 64] x 16B; s = lhi*16 + code, content = bf16x8 of
// cb[T*16+code][kk*32+lhi*8 .. +8).
__global__ void vq_prep_kernel(const float* __restrict__ cb,
                               char* __restrict__ img,
                               float* __restrict__ csq, float* __restrict__ csq1,
                               unsigned* __restrict__ cnt, unsigned* __restrict__ ovc) {
    int t = blockIdx.x * 256 + threadIdx.x;
    if (t < NROWS) cnt[t] = 0;
    if (t == 0) *ovc = 0;
    if (t < 262144) {
        int s = t & 63, kk = (t >> 6) & 7, T = t >> 9;
        int code = s & 15, lhi = s >> 4;
        const float* src = cb + (size_t)(T * 16 + code) * DIM + kk * 32 + lhi * 8;
        float4 v0 = *reinterpret_cast<const float4*>(src);
        float4 v1 = *reinterpret_cast<const float4*>(src + 4);
        uint4 o;
        o.x = pack2_bf16(v0.x, v0.y); o.y = pack2_bf16(v0.z, v0.w);
        o.z = pack2_bf16(v1.x, v1.y); o.w = pack2_bf16(v1.z, v1.w);
        *reinterpret_cast<uint4*>(img + (size_t)T * 8192 + kk * 1024 + s * 16) = o;
    } else if (t < 262144 + KCB) {
        int k = t - 262144;
        float s = np_sumsq_256(cb + (size_t)k * DIM);
        csq[k] = s;
        csq1[k] = s + 1.0f;
    }
}

// ---------------- register-streamed MFMA screen (round-9 config) ------------
// Grid 256 x 512 thr (8 waves = 2 wr x 4 wc). Wave: 64 rows x 2048 codes as
// 128 16-code tiles. B tile = 8 x dwordx4 per lane, double-buffered in NAMED
// registers; no LDS staging, no loop barriers.
__global__ __launch_bounds__(512, 2) void vq_screen_kernel(
    const float* __restrict__ z, const char* __restrict__ img,
    const float* __restrict__ csq1,
    unsigned* __restrict__ cnt, unsigned short* __restrict__ cand) {
    __shared__ unsigned runmin[128];
    __shared__ unsigned wcnt[8];
    __shared__ unsigned wbuf[8][WBUF];
    const int tid = threadIdx.x, lane = tid & 63, wid = tid >> 6;
    const int wr = wid >> 2, wc = wid & 3;
    const int l15 = lane & 15, lhi = lane >> 4;
    const int row0 = blockIdx.x * 128;
    const int tbase = wc * 128;

    // A fragments (one-time bf16 convert from raw z)
    bf16x8 ah[4][8];
    #pragma unroll
    for (int m = 0; m < 4; ++m) {
        const float* zr = z + (size_t)(row0 + wr * 64 + m * 16 + l15) * DIM;
        #pragma unroll
        for (int kk = 0; kk < 8; ++kk) {
            float4 v0 = *reinterpret_cast<const float4*>(zr + kk * 32 + lhi * 8);
            float4 v1 = *reinterpret_cast<const float4*>(zr + kk * 32 + lhi * 8 + 4);
            uint4 o;
            o.x = pack2_bf16(v0.x, v0.y); o.y = pack2_bf16(v0.z, v0.w);
            o.z = pack2_bf16(v1.x, v1.y); o.w = pack2_bf16(v1.z, v1.w);
            ah[m][kk] = __builtin_bit_cast(bf16x8, o);
        }
    }

    if (tid < 128) runmin[tid] = 0x7F800000u;   // +inf (s'' > 0 -> uint-monotone)
    if (tid < 8) wcnt[tid] = 0;
    __syncthreads();                            // the only block barrier

    f32x4 acc[4];
    #pragma unroll
    for (int m = 0; m < 4; ++m) acc[m] = (f32x4){0.f, 0.f, 0.f, 0.f};

    const char*  gp = img + (size_t)tbase * 8192 + (size_t)lane * 16;
    const float* cp = csq1 + tbase * 16 + l15;
    int codeb = tbase * 16 + l15;

    u32x4 bA[8]; float csA;
    u32x4 bB[8]; float csB;

    auto PUSH = [&](int lr, int code) {
        unsigned pi = atomicAdd(&wcnt[wid], 1u);
        if (pi < WBUF) wbuf[wid][pi] = ((unsigned)lr << 13) | (unsigned)code;
        else {
            int grow = row0 + lr;
            unsigned gs = atomicAdd(&cnt[grow], 1u);
            if (gs < CANDCAP) cand[(size_t)grow * CANDCAP + gs] = (unsigned short)code;
        }
    };

#define LOADR(bh, cs)                                                     \
    {                                                                     \
        _Pragma("unroll")                                                 \
        for (int kk = 0; kk < 8; ++kk)                                    \
            bh[kk] = *reinterpret_cast<const u32x4*>(gp + kk * 1024);     \
        cs = *cp;                                                         \
        gp += 8192; cp += 16;                                             \
    }

#define MFMAS(bh)                                                         \
    {                                                                     \
        _Pragma("unroll")                                                 \
        for (int kk = 0; kk < 8; ++kk) {                                  \
            bf16x8 bv = __builtin_bit_cast(bf16x8, bh[kk]);               \
            _Pragma("unroll")                                             \
            for (int m = 0; m < 4; ++m)                                   \
                acc[m] = __builtin_amdgcn_mfma_f32_16x16x32_bf16(         \
                    ah[m][kk], bv, acc[m], 0, 0, 0);                      \
        }                                                                 \
    }

#define EPI(csv)                                                          \
    {                                                                     \
        _Pragma("unroll")                                                 \
        for (int m = 0; m < 4; ++m) {                                     \
            const int lr0 = wr * 64 + m * 16 + lhi * 4;                   \
            uint4 rmb = *reinterpret_cast<const uint4*>(&runmin[lr0]);    \
            float s0 = fmaf(acc[m][0], -2.0f, csv);                       \
            float s1 = fmaf(acc[m][1], -2.0f, csv);                       \
            float s2 = fmaf(acc[m][2], -2.0f, csv);                       \
            float s3 = fmaf(acc[m][3], -2.0f, csv);                       \
            bool c0 = s0 < __uint_as_float(rmb.x) + MARGIN;               \
            bool c1 = s1 < __uint_as_float(rmb.y) + MARGIN;               \
            bool c2 = s2 < __uint_as_float(rmb.z) + MARGIN;               \
            bool c3 = s3 < __uint_as_float(rmb.w) + MARGIN;               \
            if (__any(c0 | c1 | c2 | c3)) {                               \
                if (c0) { if (s0 < __uint_as_float(rmb.x)) atomicMin(&runmin[lr0 + 0], __float_as_uint(s0)); PUSH(lr0 + 0, codeb); } \
                if (c1) { if (s1 < __uint_as_float(rmb.y)) atomicMin(&runmin[lr0 + 1], __float_as_uint(s1)); PUSH(lr0 + 1, codeb); } \
                if (c2) { if (s2 < __uint_as_float(rmb.z)) atomicMin(&runmin[lr0 + 2], __float_as_uint(s2)); PUSH(lr0 + 2, codeb); } \
                if (c3) { if (s3 < __uint_as_float(rmb.w)) atomicMin(&runmin[lr0 + 3], __float_as_uint(s3)); PUSH(lr0 + 3, codeb); } \
            }                                                             \
            acc[m] = (f32x4){0.f, 0.f, 0.f, 0.f};                         \
        }                                                                 \
        codeb += 16;                                                      \
    }

    LOADR(bA, csA);                  // tile 0
    LOADR(bB, csB);                  // tile 1
    MFMAS(bA);
    {   // tile 0: self-bound epilogue (runmin may still be +inf)
        #pragma unroll
        for (int m = 0; m < 4; ++m) {
            const int lr0 = wr * 64 + m * 16 + lhi * 4;
            #pragma unroll
            for (int r = 0; r < 4; ++r) {
                float s2 = fmaf(acc[m][r], -2.0f, csA);
                float sm = s2;
                sm = fminf(sm, __shfl_xor(sm, 1));
                sm = fminf(sm, __shfl_xor(sm, 2));
                sm = fminf(sm, __shfl_xor(sm, 4));
                sm = fminf(sm, __shfl_xor(sm, 8));
                if (l15 == 0) atomicMin(&runmin[lr0 + r], __float_as_uint(sm));
                if (s2 < sm + MARGIN) PUSH(lr0 + r, codeb);
            }
            acc[m] = (f32x4){0.f, 0.f, 0.f, 0.f};
        }
        codeb += 16;
    }

    for (int t = 1; t < 127; t += 2) {
        LOADR(bA, csA);  MFMAS(bB);  EPI(csB);   // tile t,   load t+1
        LOADR(bB, csB);  MFMAS(bA);  EPI(csA);   // tile t+1, load t+2
    }
    MFMAS(bB);  EPI(csB);                        // tile 127

    // flush wave-local candidate buffer to global per-row lists
    unsigned n = wcnt[wid]; if (n > WBUF) n = WBUF;
    for (unsigned e = lane; e < n; e += 64) {
        unsigned u = wbuf[wid][e];
        int row = row0 + (int)(u >> 13);
        int code = (int)(u & 8191u);
        unsigned slot = atomicAdd(&cnt[row], 1u);
        if (slot < CANDCAP) cand[(size_t)row * CANDCAP + slot] = (unsigned short)code;
    }
#undef LOADR
#undef MFMAS
#undef EPI
}

// ---------------- exact resolve + fused gather; Zr computed from LDS zrow ---
__global__ __launch_bounds__(256) void vq_exact_kernel(
    const float* __restrict__ z, const float* __restrict__ cb,
    const float* __restrict__ csq,
    const unsigned* __restrict__ cnt, const unsigned short* __restrict__ cand,
    unsigned* __restrict__ ovl, unsigned* __restrict__ ovc,
    float* __restrict__ idxF, float4* __restrict__ outz, int fused) {
    __shared__ float zrow[4][DIM];
    const int wid = threadIdx.x >> 6, lane = threadIdx.x & 63;
    const int row = blockIdx.x * 4 + wid;

    float4 zv4 = *reinterpret_cast<const float4*>(&z[(size_t)row * DIM + lane * 4]);
    *reinterpret_cast<float4*>(&zrow[wid][lane * 4]) = zv4;
    __syncthreads();

    const unsigned c = cnt[row];
    if (c == 0 || c > CANDCAP) {
        if (lane == 0) { unsigned s = atomicAdd(ovc, 1u); ovl[s] = row; }
        return;
    }

    // Zr from the LDS copy: identical bits, identical op order -> bitwise Zr.
    const float Zr = np_sumsq_256(&zrow[wid][0]);
    const float4* cb4 = reinterpret_cast<const float4*>(cb);
    float best = 3.4e38f;
    int   bi   = 0x7FFFFFFF;

    for (int j = lane; j < (int)c; j += 64) {
        int k = cand[(size_t)row * CANDCAP + j];
        float a = 0.0f;
        #pragma unroll 8
        for (int q = 0; q < 64; ++q) {
            float4 cv = cb4[(size_t)k * 64 + q];
            float4 zv = *reinterpret_cast<const float4*>(&zrow[wid][q * 4]);
            a = fmaf(zv.x, cv.x, a); a = fmaf(zv.y, cv.y, a);
            a = fmaf(zv.z, cv.z, a); a = fmaf(zv.w, cv.w, a);
        }
        float sv = __fadd_rn(__fsub_rn(Zr, __fmul_rn(2.0f, a)), csq[k]);
        if (sv < best || (sv == best && k < bi)) { best = sv; bi = k; }
    }
    #pragma unroll
    for (int mk = 32; mk >= 1; mk >>= 1) {
        float ov = __shfl_xor(best, mk);
        int   oi = __shfl_xor(bi, mk);
        if (ov < best || (ov == best && oi < bi)) { best = ov; bi = oi; }
    }
    if (lane == 0) idxF[row] = (float)bi;
    if (fused) outz[(size_t)row * 64 + lane] = cb4[(size_t)bi * 64 + lane];
}

// Full scan for overflow rows (expected 0). Bitwise chain, first-index ties.
__global__ __launch_bounds__(256) void vq_cleanup_kernel(
    const float* __restrict__ z, const float* __restrict__ cb,
    const float* __restrict__ csq,
    const unsigned* __restrict__ ovl, const unsigned* __restrict__ ovc,
    float* __restrict__ idxF, float4* __restrict__ outz, int fused) {
    __shared__ float zrow[DIM];
    __shared__ float wv[4]; __shared__ int wi[4];
    __shared__ int sbi;
    const int lane = threadIdx.x & 63, wid = threadIdx.x >> 6;
    const unsigned count = *ovc;
    for (unsigned w = blockIdx.x; w < count; w += gridDim.x) {
        const int row = ovl[w];
        __syncthreads();
        *reinterpret_cast<float4*>(&zrow[threadIdx.x * 4 & (DIM - 1)]) =
            *reinterpret_cast<const float4*>(&z[(size_t)row * DIM + (threadIdx.x * 4 & (DIM - 1))]);
        __syncthreads();
        const float Zr = np_sumsq_256(&zrow[0]);
        const float4* cb4 = reinterpret_cast<const float4*>(cb);
        float best = 3.4e38f; int bi = 0x7FFFFFFF;
        for (int k = threadIdx.x; k < KCB; k += 256) {
            float a = 0.0f;
            #pragma unroll 8
            for (int q = 0; q < 64; ++q) {
                float4 cv = cb4[(size_t)k * 64 + q];
                float4 zv = *reinterpret_cast<const float4*>(&zrow[q * 4]);
                a = fmaf(zv.x, cv.x, a); a = fmaf(zv.y, cv.y, a);
                a = fmaf(zv.z, cv.z, a); a = fmaf(zv.w, cv.w, a);
            }
            float sv = __fadd_rn(__fsub_rn(Zr, __fmul_rn(2.0f, a)), csq[k]);
            if (sv < best || (sv == best && k < bi)) { best = sv; bi = k; }
        }
        #pragma unroll
        for (int mk = 32; mk >= 1; mk >>= 1) {
            float ov = __shfl_xor(best, mk);
            int   oi = __shfl_xor(bi, mk);
            if (ov < best || (ov == best && oi < bi)) { best = ov; bi = oi; }
        }
        if (lane == 0) { wv[wid] = best; wi[wid] = bi; }
        __syncthreads();
        if (threadIdx.x == 0) {
            #pragma unroll
            for (int u = 1; u < 4; ++u)
                if (wv[u] < best || (wv[u] == best && wi[u] < bi)) { best = wv[u]; bi = wi[u]; }
            idxF[row] = (float)bi;
            sbi = bi;
        }
        __syncthreads();
        if (fused && threadIdx.x < 64)
            outz[(size_t)row * 64 + threadIdx.x] = cb4[(size_t)sbi * 64 + threadIdx.x];
    }
}

__global__ void vq_gather_kernel(const float* __restrict__ cb,
                                 const float* __restrict__ idxF,
                                 float4* __restrict__ out4) {
    int g = blockIdx.x * blockDim.x + threadIdx.x;
    const float4* cb4 = reinterpret_cast<const float4*>(cb);
    for (int i = g; i < NROWS * 64; i += gridDim.x * blockDim.x) {
        int row = i >> 6, q = i & 63;
        int idx = (int)idxF[row];
        out4[i] = cb4[(size_t)idx * 64 + q];
    }
}

extern "C" void kernel_launch(void* const* d_in, const int* in_sizes, int n_in,
                              void* d_out, int out_size, void* d_ws, size_t ws_size,
                              hipStream_t stream) {
    const float* z  = (const float*)d_in[0];
    const float* cb = (const float*)d_in[1];
    float* out = (float*)d_out;

    const int fused = (ws_size >= (size_t)SB_NEED) ? 1 : 0;
    char* SB = fused ? (char*)d_ws : (char*)d_out;

    unsigned short* candp = (unsigned short*)(SB + SB_CAND);
    unsigned*       cntp  = (unsigned*)(SB + SB_CNT);
    float*          csq   = (float*)(SB + SB_CSQ);
    float*          csq1  = (float*)(SB + SB_CSQ1);
    unsigned*       ovl   = (unsigned*)(SB + SB_OVL);
    unsigned*       ovc   = (unsigned*)(SB + SB_OVC);
    char*           img   = SB + SB_IMG;
    float*          idxF  = out + 8388608;   // output 1 (indices as float)

    vq_prep_kernel<<<(262144 + KCB + 255) / 256, 256, 0, stream>>>(
        cb, img, csq, csq1, cntp, ovc);
    vq_screen_kernel<<<NROWS / 128, 512, 0, stream>>>(z, img, csq1, cntp, candp);
    vq_exact_kernel<<<NROWS / 4, 256, 0, stream>>>(
        z, cb, csq, cntp, candp, ovl, ovc, idxF, (float4*)out, fused);
    vq_cleanup_kernel<<<64, 256, 0, stream>>>(
        z, cb, csq, ovl, ovc, idxF, (float4*)out, fused);
    if (!fused)
        vq_gather_kernel<<<2048, 256, 0, stream>>>(cb, idxF, (float4*)out);
}